// Round 6
// baseline (565.990 us; speedup 1.0000x reference)
//
#include <hip/hip_runtime.h>
#include <math.h>

// Problem constants (fixed by setup_inputs).
#define TT 16384
#define HH 4096
#define EE 256

typedef _Float16 f16x8 __attribute__((ext_vector_type(8)));
typedef float f32x4 __attribute__((ext_vector_type(4)));

// ---------------------------------------------------------------------------
// CAS-based double atomic add (fallback path only).
__device__ inline void atom_add_double(double* addr, double val) {
    unsigned long long* p = (unsigned long long*)addr;
    unsigned long long old = *p, assumed;
    do {
        assumed = old;
        double nv = __longlong_as_double(assumed) + val;
        old = atomicCAS(p, assumed, __double_as_longlong(nv));
    } while (old != assumed);
}

__global__ __launch_bounds__(64) void zero_ws_kernel(double* z) {
    if (threadIdx.x == 0) *z = 0.0;
}

__global__ __launch_bounds__(64) void finalize_z_kernel(const double* zacc,
                                                        float* zout) {
    if (threadIdx.x == 0)
        *zout = (float)(*zacc / (double)((size_t)TT * (size_t)EE));
}

// Sums 512 per-block partials.
__global__ __launch_bounds__(256) void finalize_zpart_kernel(
    const double* __restrict__ zpart, float* __restrict__ zout) {
    __shared__ double zr[256];
    zr[threadIdx.x] = zpart[threadIdx.x] + zpart[threadIdx.x + 256];
    __syncthreads();
    for (int s = 128; s > 0; s >>= 1) {
        if (threadIdx.x < s) zr[threadIdx.x] += zr[threadIdx.x + s];
        __syncthreads();
    }
    if (threadIdx.x == 0)
        *zout = (float)(zr[0] / ((double)TT * (double)EE));
}

// ---------------------------------------------------------------------------
// Prep: W (E x H fp32) -> f16 planes: hi = f16(w), lo = f16((w - hi)*2048).
__global__ __launch_bounds__(256) void prep_w_kernel(
    const float* __restrict__ w, _Float16* __restrict__ wpl)
{
    const int e = blockIdx.x;
    for (int c = threadIdx.x; c < 512; c += 256) {
        const int k = c << 3;
        const float* src = w + (size_t)e * HH + k;
        const float4 f0 = *(const float4*)src;
        const float4 f1 = *(const float4*)(src + 4);
        const float fs[8] = {f0.x, f0.y, f0.z, f0.w, f1.x, f1.y, f1.z, f1.w};
        f16x8 hi, lo;
#pragma unroll
        for (int q = 0; q < 8; ++q) {
            _Float16 h = (_Float16)fs[q];
            hi[q] = h;
            lo[q] = (_Float16)((fs[q] - (float)h) * 2048.0f);
        }
        *(f16x8*)(wpl + (size_t)e * HH + k) = hi;
        *(f16x8*)(wpl + (size_t)EE * HH + (size_t)e * HH + k) = lo;
    }
}

// ---------------------------------------------------------------------------
// MFMA GEMM v5: raw = x @ W^T via fp16 two-term split:
//   raw = sum(xh*wh) + [sum(xh*wl') + sum(xl'*wh)] / 2048      (ll dropped)
// Tile BM=64 x BN=128, BK=64 (R5 post-mortem: per-K-step time is a FIXED
// ~4.8k-cycle latency chain, invariant to per-step work and occupancy ->
// amortize it: half the steps, double the work per step).
// 512 threads = 8 waves (2M x 4N), wave-tile 32x32, 2 k-slices per step.
// Grid 512 = 2 blocks/CU. XCD-pair swizzle: bids b,b+8 share a row band's
// two column-halves on one XCD (x slab L2 reuse).
// Reg-staged + RAW barriers (lgkmcnt(0)+s_barrier, no vmcnt drain): x 2-deep
// prefetch, W-hi/W-lo 1-deep. W-lo skips LDS (per-lane from L2, ping-pong
// regs). LDS rows are 128 B (8 x 16B chunks); swizzle chunk ^= row&7 ->
// <=2-way on ds_write_b128 and fragment ds_read_b128.
// LDS per buffer 32768 B: A-hi @0 (8K), A-lo @8192 (8K), B-hi @16384 (16K).
__global__ __launch_bounds__(512, 4) void gemm_mfma_kernel(
    const float* __restrict__ x,        // (TT, HH) fp32
    const _Float16* __restrict__ wpl,   // [2][EE][HH] f16 planes
    float* __restrict__ logits,         // (TT, EE)
    double* __restrict__ zpart)         // (512) per-block z partials
{
    __shared__ __align__(16) unsigned char sm[2][32768];
    __shared__ float zred[8];

    const int tid  = threadIdx.x;
    const int lane = tid & 63;
    const int wid  = tid >> 6;          // 0..7
    const int wm   = wid >> 2;          // 0..1 (row half of 64)
    const int wn   = wid & 3;           // 0..3 (col quarter of 128)
    const int lr   = lane & 15;
    const int lc   = lane >> 4;

    // XCD-pair swizzle: xcd = bid&7; idx = bid>>3; pair (idx>>1) shares rows.
    const int bid  = blockIdx.x;
    const int rb   = ((bid & 7) << 5) + (bid >> 4);   // 0..255 row band
    const int cb   = (bid >> 3) & 1;                  // column half
    const int row0 = rb << 6;
    const int col0 = cb << 7;

    // ---- A staging (all 512 threads): 32 B of x (8 fp32) per thread/step.
    const int arow = tid >> 3, ach = tid & 7;
    const float* aSrc = x + (size_t)(row0 + arow) * HH + (ach << 3);
    const int aDst = (arow << 7) + ((ach ^ (arow & 7)) << 4);

    // ---- B-hi staging: two 16 B jobs per thread (rows r and r+64).
    const int br = tid >> 3, bch = tid & 7;
    const _Float16* bhiSrc0 = wpl + (size_t)(col0 + br) * HH + (bch << 3);
    const _Float16* bhiSrc1 = bhiSrc0 + (size_t)64 * HH;
    const int bhiDst0 = 16384 + (br << 7) + ((bch ^ (br & 7)) << 4);
    const int bhiDst1 = bhiDst0 + 8192;   // row+64: same (row&7) -> same XOR

    // ---- B-lo fragments: per-lane direct from L2 (wave-private cols).
    const _Float16* bloSrc[2];
#pragma unroll
    for (int j = 0; j < 2; ++j)
        bloSrc[j] = wpl + (size_t)EE * HH +
                    (size_t)(col0 + (wn << 5) + (j << 4) + lr) * HH + (lc << 3);

    // ---- fragment LDS read byte offsets (chunk ^= row&7 swizzle).
    int aRd[2][2], bRd[2][2];   // [i|j][ks]
#pragma unroll
    for (int i = 0; i < 2; ++i) {
        const int r = (wm << 5) + (i << 4) + lr;
#pragma unroll
        for (int ks = 0; ks < 2; ++ks)
            aRd[i][ks] = (r << 7) + ((((ks << 2) + lc) ^ (r & 7)) << 4);
    }
#pragma unroll
    for (int j = 0; j < 2; ++j) {
        const int r = (wn << 5) + (j << 4) + lr;
#pragma unroll
        for (int ks = 0; ks < 2; ++ks)
            bRd[j][ks] = 16384 + (r << 7) + ((((ks << 2) + lc) ^ (r & 7)) << 4);
    }

    f32x4 accP[2][2] = {};
    f32x4 accS[2][2] = {};
    float4 Aa0, Aa1, Ab0, Ab1;          // x prefetch, 2-deep ping-pong
    uint4 h0, h1;                       // W-hi staging regs
    f16x8 Pa[4], Pb[4];                 // W-lo frag ping-pong [j*2+ks]

#define CVT_STORE_A(SMW, X0, X1)                                              \
    {                                                                         \
        const float fs[8] = {X0.x, X0.y, X0.z, X0.w, X1.x, X1.y, X1.z, X1.w}; \
        f16x8 hi, lo;                                                         \
        _Pragma("unroll") for (int q = 0; q < 8; ++q)                         \
        {                                                                     \
            _Float16 hv = (_Float16)fs[q];                                    \
            hi[q] = hv;                                                       \
            lo[q] = (_Float16)((fs[q] - (float)hv) * 2048.0f);                \
        }                                                                     \
        *(f16x8*)((SMW) + aDst) = hi;                                         \
        *(f16x8*)((SMW) + 8192 + aDst) = lo;                                  \
    }

    // BODY(T): reads buf CUR; stages T+1 into 1-CUR; issues A(T+2)->Y,
    // Bhi(T+1)->h, Blo(T+1)->PLD; MFMAs (2 k-slices) use PUSE=Blo(T).
#define BODY(T, CUR, X0, X1, Y0, Y1, PUSE, PLD)                               \
    {                                                                         \
        if ((T) < 62) {                                                       \
            const float* ap = aSrc + (size_t)((T) + 2) * 64;                  \
            Y0 = *(const float4*)ap;                                          \
            Y1 = *(const float4*)(ap + 4);                                    \
        }                                                                     \
        if ((T) < 63) {                                                       \
            h0 = *(const uint4*)(bhiSrc0 + (size_t)((T) + 1) * 64);           \
            h1 = *(const uint4*)(bhiSrc1 + (size_t)((T) + 1) * 64);           \
            _Pragma("unroll") for (int j = 0; j < 2; ++j)                     \
                _Pragma("unroll") for (int ks = 0; ks < 2; ++ks)              \
                PLD[(j << 1) + ks] = *(const f16x8*)(                         \
                    bloSrc[j] + (size_t)((T) + 1) * 64 + (ks << 5));          \
        }                                                                     \
        const unsigned char* sb = sm[CUR];                                    \
        __builtin_amdgcn_s_setprio(1);                                        \
        _Pragma("unroll") for (int ks = 0; ks < 2; ++ks)                      \
        {                                                                     \
            f16x8 ahh[2], ahl[2], bhh[2];                                     \
            _Pragma("unroll") for (int i = 0; i < 2; ++i)                     \
            {                                                                 \
                ahh[i] = *(const f16x8*)(sb + aRd[i][ks]);                    \
                ahl[i] = *(const f16x8*)(sb + 8192 + aRd[i][ks]);             \
            }                                                                 \
            _Pragma("unroll") for (int j = 0; j < 2; ++j)                     \
                bhh[j] = *(const f16x8*)(sb + bRd[j][ks]);                    \
            _Pragma("unroll") for (int i = 0; i < 2; ++i)                     \
                _Pragma("unroll") for (int j = 0; j < 2; ++j)                 \
            {                                                                 \
                accP[i][j] = __builtin_amdgcn_mfma_f32_16x16x32_f16(          \
                    ahh[i], bhh[j], accP[i][j], 0, 0, 0);                     \
                accS[i][j] = __builtin_amdgcn_mfma_f32_16x16x32_f16(          \
                    ahh[i], PUSE[(j << 1) + ks], accS[i][j], 0, 0, 0);        \
                accS[i][j] = __builtin_amdgcn_mfma_f32_16x16x32_f16(          \
                    ahl[i], bhh[j], accS[i][j], 0, 0, 0);                     \
            }                                                                 \
        }                                                                     \
        __builtin_amdgcn_s_setprio(0);                                        \
        if ((T) < 63) {                                                       \
            unsigned char* smw = sm[1 - (CUR)];                               \
            CVT_STORE_A(smw, X0, X1);                                         \
            *(uint4*)(smw + bhiDst0) = h0;                                    \
            *(uint4*)(smw + bhiDst1) = h1;                                    \
            asm volatile("s_waitcnt lgkmcnt(0)" ::: "memory");                \
            __builtin_amdgcn_s_barrier();                                     \
        }                                                                     \
    }

    // ---- prologue: stage step 0 into buf0; preload A(1), Blo(0).
    Aa0 = *(const float4*)aSrc;
    Aa1 = *(const float4*)(aSrc + 4);
    h0 = *(const uint4*)bhiSrc0;
    h1 = *(const uint4*)bhiSrc1;
#pragma unroll
    for (int j = 0; j < 2; ++j)
#pragma unroll
        for (int ks = 0; ks < 2; ++ks)
            Pa[(j << 1) + ks] = *(const f16x8*)(bloSrc[j] + (ks << 5));
    {
        unsigned char* smw = sm[0];
        CVT_STORE_A(smw, Aa0, Aa1);
        *(uint4*)(smw + bhiDst0) = h0;
        *(uint4*)(smw + bhiDst1) = h1;
    }
    {   // reload Aa with A(1) (write above already consumed it)
        const float* ap = aSrc + 64;
        Aa0 = *(const float4*)ap;
        Aa1 = *(const float4*)(ap + 4);
    }
    asm volatile("s_waitcnt lgkmcnt(0)" ::: "memory");
    __builtin_amdgcn_s_barrier();

    for (int t = 0; t < 64; t += 2) {
        BODY(t,     0, Aa0, Aa1, Ab0, Ab1, Pa, Pb);
        BODY(t + 1, 1, Ab0, Ab1, Aa0, Aa1, Pb, Pa);
    }
#undef BODY
#undef CVT_STORE_A

    // Epilogue. C/D: col = lane&15, row = (lane>>4)*4 + reg [R1/R4-verified].
    float zs = 0.f;
#pragma unroll
    for (int i = 0; i < 2; ++i) {
        const int rb0 = row0 + (wm << 5) + (i << 4) + (lc << 2);
#pragma unroll
        for (int j = 0; j < 2; ++j) {
            const int col = col0 + (wn << 5) + (j << 4) + lr;
#pragma unroll
            for (int r = 0; r < 4; ++r) {
                const float raw =
                    accP[i][j][r] + accS[i][j][r] * 4.8828125e-4f;
                zs = fmaf(raw, raw, zs);
                logits[(size_t)(rb0 + r) * EE + col] =
                    1.f / (1.f + expf(-raw));
            }
        }
    }
#pragma unroll
    for (int d = 32; d; d >>= 1) zs += __shfl_xor(zs, d);
    if (lane == 0) zred[wid] = zs;
    __syncthreads();
    if (tid == 0) {
        double zt = 0.0;
#pragma unroll
        for (int q = 0; q < 8; ++q) zt += (double)zred[q];
        zpart[bid] = zt;
    }
}

// ---------------------------------------------------------------------------
// Fallback fp32 GEMM (first session's verified kernel) for tiny workspaces.
#define BM 32
#define BK 32
__global__ __launch_bounds__(256) void gemm_fp32_fb_kernel(
    const float* __restrict__ x, const float* __restrict__ w,
    float* __restrict__ logits, double* __restrict__ zacc)
{
    __shared__ float As[BM][BK + 1];
    __shared__ float Bs[EE][BK + 1];
    __shared__ float zred[256];

    const int tid = threadIdx.x;
    const int row0 = blockIdx.x * BM;
    const int ty = tid >> 5;
    const int tx = tid & 31;
    const int lrow = tid >> 3;
    const int lk = (tid & 7) << 2;

    float acc[4][8];
#pragma unroll
    for (int i = 0; i < 4; ++i)
#pragma unroll
        for (int j = 0; j < 8; ++j) acc[i][j] = 0.f;

    for (int k0 = 0; k0 < HH; k0 += BK) {
        float4 xa = *(const float4*)(x + (size_t)(row0 + lrow) * HH + k0 + lk);
        As[lrow][lk + 0] = xa.x;
        As[lrow][lk + 1] = xa.y;
        As[lrow][lk + 2] = xa.z;
        As[lrow][lk + 3] = xa.w;
#pragma unroll
        for (int j = 0; j < 8; ++j) {
            const int e = lrow + (j << 5);
            float4 wb = *(const float4*)(w + (size_t)e * HH + k0 + lk);
            Bs[e][lk + 0] = wb.x;
            Bs[e][lk + 1] = wb.y;
            Bs[e][lk + 2] = wb.z;
            Bs[e][lk + 3] = wb.w;
        }
        __syncthreads();
#pragma unroll 8
        for (int kk = 0; kk < BK; ++kk) {
            float a[4], bb[8];
#pragma unroll
            for (int i = 0; i < 4; ++i) a[i] = As[ty * 4 + i][kk];
#pragma unroll
            for (int j = 0; j < 8; ++j) bb[j] = Bs[tx + (j << 5)][kk];
#pragma unroll
            for (int i = 0; i < 4; ++i)
#pragma unroll
                for (int j = 0; j < 8; ++j)
                    acc[i][j] = fmaf(a[i], bb[j], acc[i][j]);
        }
        __syncthreads();
    }

    float zs = 0.f;
#pragma unroll
    for (int i = 0; i < 4; ++i) {
        const int r = row0 + ty * 4 + i;
#pragma unroll
        for (int j = 0; j < 8; ++j) {
            const float v = acc[i][j];
            zs = fmaf(v, v, zs);
            logits[(size_t)r * EE + tx + (j << 5)] = 1.f / (1.f + expf(-v));
        }
    }
    zred[tid] = zs;
    __syncthreads();
    for (int s = 128; s > 0; s >>= 1) {
        if (tid < s) zred[tid] += zred[tid + s];
        __syncthreads();
    }
    if (tid == 0) atom_add_double(zacc, (double)zred[0]);
}

// ---------------------------------------------------------------------------
// Router: one wave (64 lanes) per token; lane l owns experts 4l..4l+3.
// Matches jax.lax.top_k stability: ties broken toward the LOWER index.
__global__ __launch_bounds__(256) void router_kernel(
    const float* __restrict__ logits, const float* __restrict__ bias,
    float* __restrict__ wout, float* __restrict__ iout)
{
    const int lane = threadIdx.x & 63;
    const int wv = threadIdx.x >> 6;
    const int t = blockIdx.x * 4 + wv;

    const float* lrow = logits + (size_t)t * EE + lane * 4;
    float lg[4];
#pragma unroll
    for (int q = 0; q < 4; ++q) lg[q] = lrow[q];
    const float4 b4 = *(const float4*)(bias + lane * 4);
    const float bb[4] = {b4.x, b4.y, b4.z, b4.w};

    float sel[4];
#pragma unroll
    for (int q = 0; q < 4; ++q) sel[q] = lg[q] + bb[q];

    float m1 = sel[0], m2 = -INFINITY;
#pragma unroll
    for (int q = 1; q < 4; ++q) {
        if (sel[q] > m1) { m2 = m1; m1 = sel[q]; }
        else             { m2 = fmaxf(m2, sel[q]); }
    }
#pragma unroll
    for (int d = 1; d < 8; d <<= 1) {
        const float o1 = __shfl_xor(m1, d);
        const float o2 = __shfl_xor(m2, d);
        const float nm1 = fmaxf(m1, o1);
        const float nm2 = fmaxf(fminf(m1, o1), fmaxf(m2, o2));
        m1 = nm1; m2 = nm2;
    }
    const float gs = m1 + m2;
    const int g = lane >> 3;

    int rank = 0;
#pragma unroll
    for (int gp = 0; gp < 8; ++gp) {
        const float og = __shfl(gs, gp << 3);
        rank += (og > gs) || (og == gs && gp < g);
    }
    const bool keep = rank < 4;

    float ms[4];
#pragma unroll
    for (int q = 0; q < 4; ++q)
        ms[q] = keep ? sel[q] : -3.402823466e38f;

    float wvals[8];
    int widx[8];
#pragma unroll
    for (int it = 0; it < 8; ++it) {
        float bv = ms[0];
        int bq = 0;
#pragma unroll
        for (int q = 1; q < 4; ++q)
            if (ms[q] > bv) { bv = ms[q]; bq = q; }
        int bi = (lane << 2) + bq;
        float bl = lg[bq];
#pragma unroll
        for (int d = 1; d < 64; d <<= 1) {
            const float ov = __shfl_xor(bv, d);
            const int oi = __shfl_xor(bi, d);
            const float ol = __shfl_xor(bl, d);
            if (ov > bv || (ov == bv && oi < bi)) { bv = ov; bi = oi; bl = ol; }
        }
        wvals[it] = bl;
        widx[it] = bi;
        if ((bi >> 2) == lane) ms[bi & 3] = -INFINITY;
    }

    float s = 0.f;
#pragma unroll
    for (int it = 0; it < 8; ++it) s += wvals[it];
    s = fmaxf(s, 1e-9f);

    if (lane == 0) {
#pragma unroll
        for (int it = 0; it < 8; ++it) {
            wout[(size_t)t * 8 + it] = wvals[it] / s;
            iout[(size_t)t * 8 + it] = (float)widx[it];
        }
    }
}

// ---------------------------------------------------------------------------
extern "C" void kernel_launch(void* const* d_in, const int* in_sizes, int n_in,
                              void* d_out, int out_size, void* d_ws,
                              size_t ws_size, hipStream_t stream) {
    const float* x = (const float*)d_in[0];     // (TT, HH)
    const float* w = (const float*)d_in[1];     // (EE, HH)
    const float* bias = (const float*)d_in[2];  // (EE)

    float* out = (float*)d_out;
    float* wout = out;
    float* iout = out + (size_t)TT * 8;
    float* zout = out + (size_t)TT * 16;
    float* logits = zout + 1;
    double* zacc = (double*)d_ws;

    // ws layout: [0,8)=zacc (fb), [1024,5120)=zpart[512], [8192,..)=wpl
    const size_t need = 8192 + (size_t)2 * EE * HH * sizeof(_Float16);
    if (ws_size >= need) {
        double* zpart = (double*)((char*)d_ws + 1024);
        _Float16* wpl = (_Float16*)((char*)d_ws + 8192);
        prep_w_kernel<<<EE, 256, 0, stream>>>(w, wpl);
        gemm_mfma_kernel<<<(TT / 64) * 2, 512, 0, stream>>>(x, wpl, logits,
                                                            zpart);
        finalize_zpart_kernel<<<1, 256, 0, stream>>>(zpart, zout);
    } else {
        zero_ws_kernel<<<1, 64, 0, stream>>>(zacc);
        gemm_fp32_fb_kernel<<<TT / BM, 256, 0, stream>>>(x, w, logits, zacc);
        finalize_z_kernel<<<1, 64, 0, stream>>>(zacc, zout);
    }
    router_kernel<<<TT / 4, 256, 0, stream>>>(logits, bias, wout, iout);
}

// Round 7
// 541.141 us; speedup vs baseline: 1.0459x; 1.0459x over previous
//
#include <hip/hip_runtime.h>
#include <math.h>

// Problem constants (fixed by setup_inputs).
#define TT 16384
#define HH 4096
#define EE 256

typedef _Float16 f16x8 __attribute__((ext_vector_type(8)));
typedef float f32x4 __attribute__((ext_vector_type(4)));

// ---------------------------------------------------------------------------
// CAS-based double atomic add (fallback path only).
__device__ inline void atom_add_double(double* addr, double val) {
    unsigned long long* p = (unsigned long long*)addr;
    unsigned long long old = *p, assumed;
    do {
        assumed = old;
        double nv = __longlong_as_double(assumed) + val;
        old = atomicCAS(p, assumed, __double_as_longlong(nv));
    } while (old != assumed);
}

__global__ __launch_bounds__(64) void zero_ws_kernel(double* z) {
    if (threadIdx.x == 0) *z = 0.0;
}

__global__ __launch_bounds__(64) void finalize_z_kernel(const double* zacc,
                                                        float* zout) {
    if (threadIdx.x == 0)
        *zout = (float)(*zacc / (double)((size_t)TT * (size_t)EE));
}

// Sums 512 per-block partials.
__global__ __launch_bounds__(256) void finalize_zpart_kernel(
    const double* __restrict__ zpart, float* __restrict__ zout) {
    __shared__ double zr[256];
    zr[threadIdx.x] = zpart[threadIdx.x] + zpart[threadIdx.x + 256];
    __syncthreads();
    for (int s = 128; s > 0; s >>= 1) {
        if (threadIdx.x < s) zr[threadIdx.x] += zr[threadIdx.x + s];
        __syncthreads();
    }
    if (threadIdx.x == 0)
        *zout = (float)(zr[0] / ((double)TT * (double)EE));
}

// ---------------------------------------------------------------------------
// Prep: W (E x H fp32) -> f16 planes: hi = f16(w), lo = f16((w - hi)*2048).
__global__ __launch_bounds__(256) void prep_w_kernel(
    const float* __restrict__ w, _Float16* __restrict__ wpl)
{
    const int e = blockIdx.x;
    for (int c = threadIdx.x; c < 512; c += 256) {
        const int k = c << 3;
        const float* src = w + (size_t)e * HH + k;
        const float4 f0 = *(const float4*)src;
        const float4 f1 = *(const float4*)(src + 4);
        const float fs[8] = {f0.x, f0.y, f0.z, f0.w, f1.x, f1.y, f1.z, f1.w};
        f16x8 hi, lo;
#pragma unroll
        for (int q = 0; q < 8; ++q) {
            _Float16 h = (_Float16)fs[q];
            hi[q] = h;
            lo[q] = (_Float16)((fs[q] - (float)h) * 2048.0f);
        }
        *(f16x8*)(wpl + (size_t)e * HH + k) = hi;
        *(f16x8*)(wpl + (size_t)EE * HH + (size_t)e * HH + k) = lo;
    }
}

// ---------------------------------------------------------------------------
// MFMA GEMM v6: raw = x @ W^T via fp16 two-term split:
//   raw = sum(xh*wh) + [sum(xh*wl') + sum(xl'*wh)] / 2048      (ll dropped)
// Tile BM=64 x BN=128, BK=32. 512 threads = 8 waves (2M x 4N), wave-tile
// 32x32. Grid 512 = 2 blocks/CU. XCD-pair swizzle: bids b,b+8 share a row
// band's two column-halves on one XCD (x slab L2 reuse).
// KEY FIX vs R5: vmcnt is a FIFO. R5 issued the HBM x-loads FIRST each body,
// so the counted vmcnt before the W-hi ds_write had to drain ~900cy of HBM
// latency every step (the invariant 4.8k-cy step). New issue order:
// Blo -> Bhi -> MFMAs -> x LAST; the staging writes then wait only on L2
// loads issued a body earlier (~0 stall) and x retires during the next body.
// Also __launch_bounds__(512,2): empirically the 2nd arg acts like CUDA
// blocks/CU on hipcc (R4:92 VGPR @(512,2); R5/R6: 56/64+spills @(512,4)) --
// (512,2) caps VGPR at 128, avoiding R6's scratch-spill regression.
// LDS per buffer 16384 B: A-hi @0 (4K), A-lo @4096 (4K), B-hi @8192 (8K).
// XOR slot swizzle (c ^ (r>>1)&3) on all staged tiles -> 2-way (free) LDS.
__global__ __launch_bounds__(512, 2) void gemm_mfma_kernel(
    const float* __restrict__ x,        // (TT, HH) fp32
    const _Float16* __restrict__ wpl,   // [2][EE][HH] f16 planes
    float* __restrict__ logits,         // (TT, EE)
    double* __restrict__ zpart)         // (512) per-block z partials
{
    __shared__ __align__(16) unsigned char sm[2][16384];
    __shared__ float zred[8];

    const int tid  = threadIdx.x;
    const int lane = tid & 63;
    const int wid  = tid >> 6;          // 0..7
    const int wm   = wid >> 2;          // 0..1 (row half of 64)
    const int wn   = wid & 3;           // 0..3 (col quarter of 128)
    const int lr   = lane & 15;
    const int lc   = lane >> 4;

    // XCD-pair swizzle: xcd = bid&7; idx = bid>>3; pair (idx>>1) shares rows.
    const int bid  = blockIdx.x;
    const int rb   = ((bid & 7) << 5) + (bid >> 4);   // 0..255 row band
    const int cb   = (bid >> 3) & 1;                  // column half
    const int row0 = rb << 6;
    const int col0 = cb << 7;

    // ---- A staging (threads 0..255): 32 B of x (8 fp32) per thread/step.
    const int arow = tid >> 2, ac32 = tid & 3;
    const float* aSrc = x + (size_t)(row0 + arow) * HH + (ac32 << 3);
    const int aDst = (arow << 6) + ((ac32 ^ ((arow >> 1) & 3)) << 4);

    // ---- B-hi staging: one 16 B job per thread (rows col0..col0+127).
    const int br = tid >> 2, bc4 = tid & 3;
    const _Float16* bhiSrc = wpl + (size_t)(col0 + br) * HH + (bc4 << 3);
    const int bhiDst = 8192 + (br << 6) + ((bc4 ^ ((br >> 1) & 3)) << 4);

    // ---- B-lo fragments: per-lane direct from L2 (wave-private cols).
    const _Float16* bloSrc[2];
#pragma unroll
    for (int j = 0; j < 2; ++j)
        bloSrc[j] = wpl + (size_t)EE * HH +
                    (size_t)(col0 + (wn << 5) + (j << 4) + lr) * HH + (lc << 3);

    // ---- fragment LDS read byte offsets (2-way-free swizzled).
    int aRd[2], bRd[2];
#pragma unroll
    for (int i = 0; i < 2; ++i) {
        const int r = (wm << 5) + (i << 4) + lr;
        aRd[i] = (r << 6) + ((lc ^ ((r >> 1) & 3)) << 4);
    }
#pragma unroll
    for (int j = 0; j < 2; ++j) {
        const int r = (wn << 5) + (j << 4) + lr;
        bRd[j] = 8192 + (r << 6) + ((lc ^ ((r >> 1) & 3)) << 4);
    }

    f32x4 accP[2][2] = {};
    f32x4 accS[2][2] = {};
    float4 Aa0, Aa1, Ab0, Ab1;          // x prefetch, 2-deep ping-pong
    uint4 h0;                           // W-hi staging reg
    f16x8 Pa[2], Pb[2];                 // W-lo fragment ping-pong

#define CVT_STORE_A(SMW, X0, X1)                                              \
    if (tid < 256) {                                                          \
        const float fs[8] = {X0.x, X0.y, X0.z, X0.w, X1.x, X1.y, X1.z, X1.w}; \
        f16x8 hi, lo;                                                         \
        _Pragma("unroll") for (int q = 0; q < 8; ++q)                         \
        {                                                                     \
            _Float16 hv = (_Float16)fs[q];                                    \
            hi[q] = hv;                                                       \
            lo[q] = (_Float16)((fs[q] - (float)hv) * 2048.0f);                \
        }                                                                     \
        *(f16x8*)((SMW) + aDst) = hi;                                         \
        *(f16x8*)((SMW) + 4096 + aDst) = lo;                                  \
    }

    // BODY(T): reads buf CUR; stages T+1 into 1-CUR at end.
    // vmem ISSUE ORDER (FIFO discipline): Blo(T+1), Bhi(T+1) [L2, needed by
    // this body's end-writes], then MFMAs, then x(T+2) [HBM, needed 1.5
    // bodies later] LAST so the end-write vmcnt never drains it.
#define BODY(T, CUR, X0, X1, Y0, Y1, PUSE, PLD)                               \
    {                                                                         \
        if ((T) < 127) {                                                      \
            _Pragma("unroll") for (int j = 0; j < 2; ++j)                     \
                PLD[j] = *(const f16x8*)(bloSrc[j] + (size_t)((T) + 1) * 32); \
            h0 = *(const uint4*)(bhiSrc + (size_t)((T) + 1) * 32);            \
        }                                                                     \
        const unsigned char* sb = sm[CUR];                                    \
        f16x8 ahh[2], ahl[2], bhh[2];                                         \
        _Pragma("unroll") for (int i = 0; i < 2; ++i)                         \
        {                                                                     \
            ahh[i] = *(const f16x8*)(sb + aRd[i]);                            \
            ahl[i] = *(const f16x8*)(sb + 4096 + aRd[i]);                     \
        }                                                                     \
        _Pragma("unroll") for (int j = 0; j < 2; ++j)                         \
            bhh[j] = *(const f16x8*)(sb + bRd[j]);                            \
        __builtin_amdgcn_s_setprio(1);                                        \
        _Pragma("unroll") for (int i = 0; i < 2; ++i)                         \
            _Pragma("unroll") for (int j = 0; j < 2; ++j)                     \
        {                                                                     \
            accP[i][j] = __builtin_amdgcn_mfma_f32_16x16x32_f16(              \
                ahh[i], bhh[j], accP[i][j], 0, 0, 0);                         \
            accS[i][j] = __builtin_amdgcn_mfma_f32_16x16x32_f16(              \
                ahh[i], PUSE[j], accS[i][j], 0, 0, 0);                        \
            accS[i][j] = __builtin_amdgcn_mfma_f32_16x16x32_f16(              \
                ahl[i], bhh[j], accS[i][j], 0, 0, 0);                         \
        }                                                                     \
        __builtin_amdgcn_s_setprio(0);                                        \
        if ((T) < 126 && tid < 256) {                                         \
            const float* ap = aSrc + (size_t)((T) + 2) * 32;                  \
            Y0 = *(const float4*)ap;                                          \
            Y1 = *(const float4*)(ap + 4);                                    \
        }                                                                     \
        if ((T) < 127) {                                                      \
            unsigned char* smw = sm[1 - (CUR)];                               \
            CVT_STORE_A(smw, X0, X1);                                         \
            *(uint4*)(smw + bhiDst) = h0;                                     \
            asm volatile("s_waitcnt lgkmcnt(0)" ::: "memory");                \
            __builtin_amdgcn_s_barrier();                                     \
        }                                                                     \
    }

    // ---- prologue: stage step 0 into buf0; preload A(1), Blo(0).
#pragma unroll
    for (int j = 0; j < 2; ++j) Pa[j] = *(const f16x8*)bloSrc[j];
    h0 = *(const uint4*)bhiSrc;
    if (tid < 256) {
        Aa0 = *(const float4*)aSrc;
        Aa1 = *(const float4*)(aSrc + 4);
    }
    {
        unsigned char* smw = sm[0];
        CVT_STORE_A(smw, Aa0, Aa1);
        *(uint4*)(smw + bhiDst) = h0;
    }
    if (tid < 256) {   // reload Aa with A(1) (write above already consumed it)
        const float* ap = aSrc + 32;
        Aa0 = *(const float4*)ap;
        Aa1 = *(const float4*)(ap + 4);
    }
    asm volatile("s_waitcnt lgkmcnt(0)" ::: "memory");
    __builtin_amdgcn_s_barrier();

    for (int t = 0; t < 128; t += 2) {
        BODY(t,     0, Aa0, Aa1, Ab0, Ab1, Pa, Pb);
        BODY(t + 1, 1, Ab0, Ab1, Aa0, Aa1, Pb, Pa);
    }
#undef BODY
#undef CVT_STORE_A

    // Epilogue. C/D: col = lane&15, row = (lane>>4)*4 + reg [R1/R4-verified].
    float zs = 0.f;
#pragma unroll
    for (int i = 0; i < 2; ++i) {
        const int rb0 = row0 + (wm << 5) + (i << 4) + (lc << 2);
#pragma unroll
        for (int j = 0; j < 2; ++j) {
            const int col = col0 + (wn << 5) + (j << 4) + lr;
#pragma unroll
            for (int r = 0; r < 4; ++r) {
                const float raw =
                    accP[i][j][r] + accS[i][j][r] * 4.8828125e-4f;
                zs = fmaf(raw, raw, zs);
                logits[(size_t)(rb0 + r) * EE + col] =
                    1.f / (1.f + expf(-raw));
            }
        }
    }
#pragma unroll
    for (int d = 32; d; d >>= 1) zs += __shfl_xor(zs, d);
    if (lane == 0) zred[wid] = zs;
    __syncthreads();
    if (tid == 0) {
        double zt = 0.0;
#pragma unroll
        for (int q = 0; q < 8; ++q) zt += (double)zred[q];
        zpart[bid] = zt;
    }
}

// ---------------------------------------------------------------------------
// Fallback fp32 GEMM (first session's verified kernel) for tiny workspaces.
#define BM 32
#define BK 32
__global__ __launch_bounds__(256) void gemm_fp32_fb_kernel(
    const float* __restrict__ x, const float* __restrict__ w,
    float* __restrict__ logits, double* __restrict__ zacc)
{
    __shared__ float As[BM][BK + 1];
    __shared__ float Bs[EE][BK + 1];
    __shared__ float zred[256];

    const int tid = threadIdx.x;
    const int row0 = blockIdx.x * BM;
    const int ty = tid >> 5;
    const int tx = tid & 31;
    const int lrow = tid >> 3;
    const int lk = (tid & 7) << 2;

    float acc[4][8];
#pragma unroll
    for (int i = 0; i < 4; ++i)
#pragma unroll
        for (int j = 0; j < 8; ++j) acc[i][j] = 0.f;

    for (int k0 = 0; k0 < HH; k0 += BK) {
        float4 xa = *(const float4*)(x + (size_t)(row0 + lrow) * HH + k0 + lk);
        As[lrow][lk + 0] = xa.x;
        As[lrow][lk + 1] = xa.y;
        As[lrow][lk + 2] = xa.z;
        As[lrow][lk + 3] = xa.w;
#pragma unroll
        for (int j = 0; j < 8; ++j) {
            const int e = lrow + (j << 5);
            float4 wb = *(const float4*)(w + (size_t)e * HH + k0 + lk);
            Bs[e][lk + 0] = wb.x;
            Bs[e][lk + 1] = wb.y;
            Bs[e][lk + 2] = wb.z;
            Bs[e][lk + 3] = wb.w;
        }
        __syncthreads();
#pragma unroll 8
        for (int kk = 0; kk < BK; ++kk) {
            float a[4], bb[8];
#pragma unroll
            for (int i = 0; i < 4; ++i) a[i] = As[ty * 4 + i][kk];
#pragma unroll
            for (int j = 0; j < 8; ++j) bb[j] = Bs[tx + (j << 5)][kk];
#pragma unroll
            for (int i = 0; i < 4; ++i)
#pragma unroll
                for (int j = 0; j < 8; ++j)
                    acc[i][j] = fmaf(a[i], bb[j], acc[i][j]);
        }
        __syncthreads();
    }

    float zs = 0.f;
#pragma unroll
    for (int i = 0; i < 4; ++i) {
        const int r = row0 + ty * 4 + i;
#pragma unroll
        for (int j = 0; j < 8; ++j) {
            const float v = acc[i][j];
            zs = fmaf(v, v, zs);
            logits[(size_t)r * EE + tx + (j << 5)] = 1.f / (1.f + expf(-v));
        }
    }
    zred[tid] = zs;
    __syncthreads();
    for (int s = 128; s > 0; s >>= 1) {
        if (tid < s) zred[tid] += zred[tid + s];
        __syncthreads();
    }
    if (tid == 0) atom_add_double(zacc, (double)zred[0]);
}

// ---------------------------------------------------------------------------
// Router: one wave (64 lanes) per token; lane l owns experts 4l..4l+3.
// Matches jax.lax.top_k stability: ties broken toward the LOWER index.
__global__ __launch_bounds__(256) void router_kernel(
    const float* __restrict__ logits, const float* __restrict__ bias,
    float* __restrict__ wout, float* __restrict__ iout)
{
    const int lane = threadIdx.x & 63;
    const int wv = threadIdx.x >> 6;
    const int t = blockIdx.x * 4 + wv;

    const float* lrow = logits + (size_t)t * EE + lane * 4;
    float lg[4];
#pragma unroll
    for (int q = 0; q < 4; ++q) lg[q] = lrow[q];
    const float4 b4 = *(const float4*)(bias + lane * 4);
    const float bb[4] = {b4.x, b4.y, b4.z, b4.w};

    float sel[4];
#pragma unroll
    for (int q = 0; q < 4; ++q) sel[q] = lg[q] + bb[q];

    float m1 = sel[0], m2 = -INFINITY;
#pragma unroll
    for (int q = 1; q < 4; ++q) {
        if (sel[q] > m1) { m2 = m1; m1 = sel[q]; }
        else             { m2 = fmaxf(m2, sel[q]); }
    }
#pragma unroll
    for (int d = 1; d < 8; d <<= 1) {
        const float o1 = __shfl_xor(m1, d);
        const float o2 = __shfl_xor(m2, d);
        const float nm1 = fmaxf(m1, o1);
        const float nm2 = fmaxf(fminf(m1, o1), fmaxf(m2, o2));
        m1 = nm1; m2 = nm2;
    }
    const float gs = m1 + m2;
    const int g = lane >> 3;

    int rank = 0;
#pragma unroll
    for (int gp = 0; gp < 8; ++gp) {
        const float og = __shfl(gs, gp << 3);
        rank += (og > gs) || (og == gs && gp < g);
    }
    const bool keep = rank < 4;

    float ms[4];
#pragma unroll
    for (int q = 0; q < 4; ++q)
        ms[q] = keep ? sel[q] : -3.402823466e38f;

    float wvals[8];
    int widx[8];
#pragma unroll
    for (int it = 0; it < 8; ++it) {
        float bv = ms[0];
        int bq = 0;
#pragma unroll
        for (int q = 1; q < 4; ++q)
            if (ms[q] > bv) { bv = ms[q]; bq = q; }
        int bi = (lane << 2) + bq;
        float bl = lg[bq];
#pragma unroll
        for (int d = 1; d < 64; d <<= 1) {
            const float ov = __shfl_xor(bv, d);
            const int oi = __shfl_xor(bi, d);
            const float ol = __shfl_xor(bl, d);
            if (ov > bv || (ov == bv && oi < bi)) { bv = ov; bi = oi; bl = ol; }
        }
        wvals[it] = bl;
        widx[it] = bi;
        if ((bi >> 2) == lane) ms[bi & 3] = -INFINITY;
    }

    float s = 0.f;
#pragma unroll
    for (int it = 0; it < 8; ++it) s += wvals[it];
    s = fmaxf(s, 1e-9f);

    if (lane == 0) {
#pragma unroll
        for (int it = 0; it < 8; ++it) {
            wout[(size_t)t * 8 + it] = wvals[it] / s;
            iout[(size_t)t * 8 + it] = (float)widx[it];
        }
    }
}

// ---------------------------------------------------------------------------
extern "C" void kernel_launch(void* const* d_in, const int* in_sizes, int n_in,
                              void* d_out, int out_size, void* d_ws,
                              size_t ws_size, hipStream_t stream) {
    const float* x = (const float*)d_in[0];     // (TT, HH)
    const float* w = (const float*)d_in[1];     // (EE, HH)
    const float* bias = (const float*)d_in[2];  // (EE)

    float* out = (float*)d_out;
    float* wout = out;
    float* iout = out + (size_t)TT * 8;
    float* zout = out + (size_t)TT * 16;
    float* logits = zout + 1;
    double* zacc = (double*)d_ws;

    // ws layout: [0,8)=zacc (fb), [1024,5120)=zpart[512], [8192,..)=wpl
    const size_t need = 8192 + (size_t)2 * EE * HH * sizeof(_Float16);
    if (ws_size >= need) {
        double* zpart = (double*)((char*)d_ws + 1024);
        _Float16* wpl = (_Float16*)((char*)d_ws + 8192);
        prep_w_kernel<<<EE, 256, 0, stream>>>(w, wpl);
        gemm_mfma_kernel<<<(TT / 64) * 2, 512, 0, stream>>>(x, wpl, logits,
                                                            zpart);
        finalize_zpart_kernel<<<1, 256, 0, stream>>>(zpart, zout);
    } else {
        zero_ws_kernel<<<1, 64, 0, stream>>>(zacc);
        gemm_fp32_fb_kernel<<<TT / BM, 256, 0, stream>>>(x, w, logits, zacc);
        finalize_z_kernel<<<1, 64, 0, stream>>>(zacc, zout);
    }
    router_kernel<<<TT / 4, 256, 0, stream>>>(logits, bias, wout, iout);
}